// Round 11
// baseline (482.831 us; speedup 1.0000x reference)
//
#include <hip/hip_runtime.h>
#include <stdint.h>

// Problem dims (fixed)
#define BB 64
#define TT 32
#define EE 512
#define HH 512
#define VV 32000
#define G4 2048

typedef _Float16 f16x8 __attribute__((ext_vector_type(8)));
typedef float f32x4 __attribute__((ext_vector_type(4)));

__device__ __forceinline__ unsigned short f2h(float f) {
  return __builtin_bit_cast(unsigned short, (_Float16)f);   // RNE hw cvt
}
__device__ __forceinline__ void gload_lds16(const unsigned short* g, unsigned short* l) {
  __builtin_amdgcn_global_load_lds((const __attribute__((address_space(1))) void*)g,
                                   (__attribute__((address_space(3))) void*)l, 16, 0, 0);
}
__device__ __forceinline__ float sigm(float x) { return 1.f / (1.f + __expf(-x)); }
__device__ __forceinline__ float tanh_fast(float x) {
  return 1.f - 2.f / (__expf(2.f * x) + 1.f);   // stable at +-inf
}

// ---------------------------------------------------------------------------
// Kernel 1: Gpre(2112 x 2048) = [feat; emb[cap]] @ W_ih.T + (b_ih + b_hh) [fp32]
// (unchanged, verified r2-r10)
// ---------------------------------------------------------------------------
__global__ __launch_bounds__(256) void k_gemm_ih(const float* __restrict__ feat,
                                                 const int* __restrict__ cap,
                                                 const float* __restrict__ emb,
                                                 const float* __restrict__ Bw,
                                                 const float* __restrict__ bih,
                                                 const float* __restrict__ bhh,
                                                 float* __restrict__ C) {
  __shared__ float As[16][128];
  __shared__ float Bs[16][128];
  const int tid = threadIdx.x;
  const int bx = blockIdx.x & 15;   // n tile 0..15
  const int by = blockIdx.x >> 4;   // m tile 0..16
  const int m0 = by * 128, n0 = bx * 128;
  const int tx = tid & 15, ty = tid >> 4;

  float acc[8][8];
#pragma unroll
  for (int i = 0; i < 8; i++)
#pragma unroll
    for (int j = 0; j < 8; j++) acc[i][j] = 0.f;

  const int lr = tid >> 1;           // row-in-tile 0..127
  const int lk = (tid & 1) * 8;      // 0 or 8
  int arow = m0 + lr; if (arow > 2111) arow = 2111;  // clamp (store guarded)
  const float* Ap;
  if (arow < BB) {
    Ap = feat + (size_t)arow * EE + lk;
  } else {
    int idx = arow - BB;
    int t = idx >> 6, b = idx & 63;
    Ap = emb + (size_t)cap[b * TT + t] * EE + lk;
  }
  const int brow = n0 + lr;          // < 2048 always
  const float* Bp = Bw + (size_t)brow * EE + lk;

  for (int k0 = 0; k0 < EE; k0 += 16) {
    float4 a0 = *(const float4*)(Ap + k0);
    float4 a1 = *(const float4*)(Ap + k0 + 4);
    float4 b0 = *(const float4*)(Bp + k0);
    float4 b1 = *(const float4*)(Bp + k0 + 4);
    __syncthreads();
    As[lk + 0][lr] = a0.x; As[lk + 1][lr] = a0.y; As[lk + 2][lr] = a0.z; As[lk + 3][lr] = a0.w;
    As[lk + 4][lr] = a1.x; As[lk + 5][lr] = a1.y; As[lk + 6][lr] = a1.z; As[lk + 7][lr] = a1.w;
    Bs[lk + 0][lr] = b0.x; Bs[lk + 1][lr] = b0.y; Bs[lk + 2][lr] = b0.z; Bs[lk + 3][lr] = b0.w;
    Bs[lk + 4][lr] = b1.x; Bs[lk + 5][lr] = b1.y; Bs[lk + 6][lr] = b1.z; Bs[lk + 7][lr] = b1.w;
    __syncthreads();
#pragma unroll
    for (int k = 0; k < 16; k++) {
      float a[8], b[8];
      *(float4*)&a[0] = *(const float4*)&As[k][ty * 8];
      *(float4*)&a[4] = *(const float4*)&As[k][ty * 8 + 4];
      *(float4*)&b[0] = *(const float4*)&Bs[k][tx * 8];
      *(float4*)&b[4] = *(const float4*)&Bs[k][tx * 8 + 4];
#pragma unroll
      for (int i = 0; i < 8; i++)
#pragma unroll
        for (int j = 0; j < 8; j++) acc[i][j] += a[i] * b[j];
    }
  }

  float bs[8];
#pragma unroll
  for (int j = 0; j < 8; j++) {
    int n = n0 + tx * 8 + j;
    bs[j] = bih[n] + bhh[n];
  }
#pragma unroll
  for (int i = 0; i < 8; i++) {
    int m = m0 + ty * 8 + i;
    if (m < 2112) {
      float4 o0, o1;
      o0.x = acc[i][0] + bs[0]; o0.y = acc[i][1] + bs[1];
      o0.z = acc[i][2] + bs[2]; o0.w = acc[i][3] + bs[3];
      o1.x = acc[i][4] + bs[4]; o1.y = acc[i][5] + bs[5];
      o1.z = acc[i][6] + bs[6]; o1.w = acc[i][7] + bs[7];
      *(float4*)(C + (size_t)m * G4 + n0 + tx * 8) = o0;
      *(float4*)(C + (size_t)m * G4 + n0 + tx * 8 + 4) = o1;
    }
  }
}

// ---------------------------------------------------------------------------
// Kernel 2: zero sync flags: arr(64 lines) + done(16) + xflag(8) + claim(8)
// ---------------------------------------------------------------------------
__global__ void k_zero(int* f) {
  for (int i = threadIdx.x; i < 3072; i += 256)
    __hip_atomic_store(&f[i], 0, __ATOMIC_RELAXED, __HIP_MEMORY_SCOPE_AGENT);
}

// ---------------------------------------------------------------------------
// Tree barrier (r10, proven): arr per-block lines -> block0 gathers -> done
// replicated on 16 lines. Block 0 must also aggregate final phase TT+1.
// ---------------------------------------------------------------------------
__device__ __forceinline__ void agg_phase(int* arr, int* done, int tid, int p) {
  if (tid < 64) {
    for (;;) {
      int v = __hip_atomic_load(&arr[tid * 32], __ATOMIC_RELAXED, __HIP_MEMORY_SCOPE_AGENT);
      if (__all(v >= p)) break;
      __builtin_amdgcn_s_sleep(1);
    }
    if (tid == 0) {
#pragma unroll
      for (int c = 0; c < 16; ++c)
        __hip_atomic_store(&done[c * 32], p, __ATOMIC_RELAXED, __HIP_MEMORY_SCOPE_AGENT);
    }
  }
}

__device__ __forceinline__ void tree_wait(int* arr, int* done, int bid, int tid, int p) {
  if (bid == 0) {
    agg_phase(arr, done, tid, p);
  } else if (tid == 0) {
    while (__hip_atomic_load(&done[(bid & 15) * 32], __ATOMIC_RELAXED,
                             __HIP_MEMORY_SCOPE_AGENT) < p)
      __builtin_amdgcn_s_sleep(1);
  }
  __syncthreads();
}

// ---------------------------------------------------------------------------
// Kernel 3: FUSED persistent recurrence + out-projection (r10 + XCD relay).
// Blocks 0..63 (rnn role): unchanged r10 (W_hh fp16 LDS, 16 MFMA/step, c in
//   regs, packed-u32 agent-atomic h stores, tree barrier).
// Blocks 64..255 (out role): one relay block per PHYSICAL XCD (elected via
//   CAS on claim[xcc], xcc from s_getreg HW_REG_XCC_ID) copies hseq[s] ->
//   hrelay[xcc][s] with plain stores (lands in local L2), publishes
//   xflag[xcc]; the other out blocks on that XCD stage h from hrelay =
//   L2 HITS. Kills the 192-block coherence-point herd that stalled the rnn
//   chain (r6 7.9 us/step solo vs r10 11.6 fused). W_out in regs unchanged.
// ---------------------------------------------------------------------------
__global__ __launch_bounds__(512) void k_fused(const float* __restrict__ Gpre,
                                               const float* __restrict__ Whh,
                                               const float* __restrict__ Wout,
                                               const float* __restrict__ bout,
                                               char* hseq_base,
                                               unsigned short* __restrict__ hrelay,
                                               float* __restrict__ out,
                                               int* __restrict__ flags) {
  __shared__ __align__(16) char lds_raw[65536];
  __shared__ int relay_sh;
  unsigned short* hseq16 = (unsigned short*)hseq_base;
  unsigned int* hseq32 = (unsigned int*)hseq_base;
  int* arr = flags;
  int* done = flags + 2048;

  const int tid = threadIdx.x;
  const int bid = blockIdx.x;
  const int l = tid & 63;
  const int w = tid >> 6;

  if (bid < 64) {
    // ======================= RNN role =======================
    unsigned short* W_lds = (unsigned short*)lds_raw;        // 32 KB
    float* gate_buf = (float*)(lds_raw + 32768);             // 8 KB
    const int u0 = bid * 8;
    const int lr = l & 15;
    const int kc = l >> 4;
    const int nt = w & 1;
    const int mt = w >> 1;
    const int es = w * 8 + (l >> 3);
    const int edu = l & 7;

    // stage W_hh (f32 -> fp16) into LDS, chunk-XOR swizzled
    {
      int row = tid >> 4;            // 0..31 (= g*8 + du)
      int sub = tid & 15;
      int g = row >> 3, du = row & 7;
      const float* srcp = Whh + (size_t)(g * 512 + u0 + du) * HH;
#pragma unroll
      for (int c0 = 0; c0 < 4; ++c0) {
        int c = sub * 4 + c0;
        float4 va = *(const float4*)(srcp + c * 8);
        float4 vb = *(const float4*)(srcp + c * 8 + 4);
        __align__(16) unsigned short t8[8];
        t8[0] = f2h(va.x); t8[1] = f2h(va.y); t8[2] = f2h(va.z); t8[3] = f2h(va.w);
        t8[4] = f2h(vb.x); t8[5] = f2h(vb.y); t8[6] = f2h(vb.z); t8[7] = f2h(vb.w);
        *(int4*)((char*)W_lds + row * 1024 + ((c ^ (row & 7)) * 16)) = *(const int4*)t8;
      }
    }

    // prime (h=c=0)
    float c_reg;
    {
      const float* gp = Gpre + (size_t)es * G4 + u0 + edu;
      float gi = gp[0], gg = gp[1024], go = gp[1536];
      float cn = sigm(gi) * tanh_fast(gg);
      float hn = sigm(go) * tanh_fast(cn);
      c_reg = cn;
      unsigned int hb = f2h(hn);
      unsigned int other = (unsigned int)__shfl_xor((int)hb, 1);
      if (!(l & 1))
        __hip_atomic_store(&hseq32[(size_t)es * 256 + bid * 4 + (edu >> 1)],
                           hb | (other << 16), __ATOMIC_RELAXED, __HIP_MEMORY_SCOPE_AGENT);
    }
    asm volatile("s_waitcnt vmcnt(0)" ::: "memory");
    __syncthreads();
    if (tid == 0)
      __hip_atomic_store(&arr[bid * 32], 1, __ATOMIC_RELAXED, __HIP_MEMORY_SCOPE_AGENT);

    float pre[4];
#pragma unroll
    for (int g = 0; g < 4; ++g)
      pre[g] = Gpre[((size_t)64 + es) * G4 + g * 512 + u0 + edu];

    tree_wait(arr, done, bid, tid, 1);

    for (int s = 1; s <= TT; ++s) {
      const unsigned short* hin = hseq16 + (size_t)(s - 1) * BB * HH;
      f32x4 acca = {0.f, 0.f, 0.f, 0.f};
      f32x4 accb = {0.f, 0.f, 0.f, 0.f};
      const unsigned short* hbase = hin + (size_t)(mt * 16 + lr) * HH + kc * 8;
      const int wrow = nt * 16 + lr;
      const char* wbase = (const char*)W_lds + wrow * 1024;
#pragma unroll
      for (int kk = 0; kk < 8; ++kk) {
        uint4 hq0 = *(const uint4*)(hbase + kk * 32);
        int4 wq0 = *(const int4*)(wbase + (((kk * 4 + kc) ^ (wrow & 7)) * 16));
        acca = __builtin_amdgcn_mfma_f32_16x16x32_f16(
            __builtin_bit_cast(f16x8, hq0), __builtin_bit_cast(f16x8, wq0), acca, 0, 0, 0);
        uint4 hq1 = *(const uint4*)(hbase + (kk + 8) * 32);
        int4 wq1 = *(const int4*)(wbase + ((((kk + 8) * 4 + kc) ^ (wrow & 7)) * 16));
        accb = __builtin_amdgcn_mfma_f32_16x16x32_f16(
            __builtin_bit_cast(f16x8, hq1), __builtin_bit_cast(f16x8, wq1), accb, 0, 0, 0);
      }
      f32x4 acc;
#pragma unroll
      for (int j = 0; j < 4; ++j) acc[j] = acca[j] + accb[j];

      // gate partials -> LDS (XOR-swizzled on sample index)
      {
        int g = nt * 2 + (lr >> 3);
        int du = lr & 7;
#pragma unroll
        for (int j = 0; j < 4; ++j) {
          int ss = mt * 16 + kc * 4 + j;
          gate_buf[g * 512 + du * 64 + (ss ^ (du << 3))] = acc[j];
        }
      }
      __syncthreads();

      // epilogue: one (es, edu) update per thread
      {
        float gi = gate_buf[0 * 512 + edu * 64 + (es ^ (edu << 3))] + pre[0];
        float gf = gate_buf[1 * 512 + edu * 64 + (es ^ (edu << 3))] + pre[1];
        float gg = gate_buf[2 * 512 + edu * 64 + (es ^ (edu << 3))] + pre[2];
        float go = gate_buf[3 * 512 + edu * 64 + (es ^ (edu << 3))] + pre[3];
        float cn = sigm(gf) * c_reg + sigm(gi) * tanh_fast(gg);
        float hn = sigm(go) * tanh_fast(cn);
        c_reg = cn;
        unsigned int hb = f2h(hn);
        unsigned int other = (unsigned int)__shfl_xor((int)hb, 1);
        if (!(l & 1))
          __hip_atomic_store(&hseq32[(size_t)s * 16384 + es * 256 + bid * 4 + (edu >> 1)],
                             hb | (other << 16), __ATOMIC_RELAXED, __HIP_MEMORY_SCOPE_AGENT);
      }
      asm volatile("s_waitcnt vmcnt(0)" ::: "memory");
      __syncthreads();
      if (tid == 0)
        __hip_atomic_store(&arr[bid * 32], s + 1, __ATOMIC_RELAXED, __HIP_MEMORY_SCOPE_AGENT);

      if (s < TT) {
#pragma unroll
        for (int g = 0; g < 4; ++g)
          pre[g] = Gpre[((size_t)(s + 1) * 64 + es) * G4 + g * 512 + u0 + edu];
        tree_wait(arr, done, bid, tid, s + 1);
      }
    }

    // FINAL aggregate: relays wait for done == TT+1.
    if (bid == 0) agg_phase(arr, done, tid, TT + 1);
  } else {
    // ======================= OUT role =======================
    unsigned short* As = (unsigned short*)lds_raw;           // 64 KB: h_s staged
    const int slice0 = bid - 64;           // 0..191
    const bool two = (slice0 < 58);        // +192 -> slices 192..249
    const int n00 = slice0 * 128;
    const int n01 = (two ? (slice0 + 192) : slice0) * 128;
    const int bcol = w * 16 + (l >> 4) * 4;
    const float4 bo0 = *(const float4*)(bout + n00 + bcol);
    const float4 bo1 = *(const float4*)(bout + n01 + bcol);

    // ---- physical XCD id + relay election (one relay per XCD) ----
    int xcc;
    asm volatile("s_getreg_b32 %0, hwreg(HW_REG_XCC_ID)" : "=s"(xcc));
    xcc &= 7;
    int* xflag = flags + 2560 + xcc * 32;
    int* claim = flags + 2816 + xcc * 32;
    if (tid == 0) {
      int expected = 0;
      bool won = __hip_atomic_compare_exchange_strong(
          claim, &expected, 1, __ATOMIC_RELAXED, __ATOMIC_RELAXED, __HIP_MEMORY_SCOPE_AGENT);
      relay_sh = won ? 1 : 0;
    }
    __syncthreads();
    const bool isRelay = (relay_sh != 0);
    unsigned short* hrbase = hrelay + (size_t)xcc * 33 * (BB * HH);

    // ---- preload W_out slice(s) f32 -> f16 fragments in REGISTERS (once) ----
    const int vr0 = n00 + w * 16 + (l & 15);
    const int vr1 = n01 + w * 16 + (l & 15);
    const int kb = (l >> 4) * 8;
    uint4 w0r[16], w1r[16];
#pragma unroll
    for (int kt = 0; kt < 16; ++kt) {
      const float* p = Wout + (size_t)vr0 * HH + kt * 32 + kb;
      float4 a = *(const float4*)p;
      float4 b = *(const float4*)(p + 4);
      __align__(16) unsigned short t8[8];
      t8[0] = f2h(a.x); t8[1] = f2h(a.y); t8[2] = f2h(a.z); t8[3] = f2h(a.w);
      t8[4] = f2h(b.x); t8[5] = f2h(b.y); t8[6] = f2h(b.z); t8[7] = f2h(b.w);
      w0r[kt] = *(const uint4*)t8;
    }
    if (two) {
#pragma unroll
      for (int kt = 0; kt < 16; ++kt) {
        const float* p = Wout + (size_t)vr1 * HH + kt * 32 + kb;
        float4 a = *(const float4*)p;
        float4 b = *(const float4*)(p + 4);
        __align__(16) unsigned short t8[8];
        t8[0] = f2h(a.x); t8[1] = f2h(a.y); t8[2] = f2h(a.z); t8[3] = f2h(a.w);
        t8[4] = f2h(b.x); t8[5] = f2h(b.y); t8[6] = f2h(b.z); t8[7] = f2h(b.w);
        w1r[kt] = *(const uint4*)t8;
      }
    }

    for (int s = 1; s <= TT; ++s) {
      const unsigned short* hs = hseq16 + (size_t)s * BB * HH;
      unsigned short* hr = hrbase + (size_t)s * (BB * HH);

      if (isRelay) {
        // wait for rnn completion of step s, then broadcast h into local L2
        if (tid == 0) {
          while (__hip_atomic_load(&done[(bid & 15) * 32], __ATOMIC_RELAXED,
                                   __HIP_MEMORY_SCOPE_AGENT) < s + 1)
            __builtin_amdgcn_s_sleep(2);
        }
        __syncthreads();
#pragma unroll
        for (int it = 0; it < 8; ++it)
          ((uint4*)hr)[it * 512 + tid] = ((const uint4*)hs)[it * 512 + tid];
        asm volatile("s_waitcnt vmcnt(0)" ::: "memory");
        __syncthreads();
        if (tid == 0)
          __hip_atomic_store(xflag, s + 1, __ATOMIC_RELAXED, __HIP_MEMORY_SCOPE_AGENT);
        // stage own As from hs (now L2-warm from the copy reads)
#pragma unroll
        for (int it = 0; it < 8; ++it) {
          int ci = it * 512 + tid;
          int row = ci >> 6, cd = ci & 63;
          gload_lds16(hs + (size_t)row * 512 + (cd ^ (row & 7)) * 8, As + ci * 8);
        }
      } else {
        // wait for this XCD's relay, then stage from L2-resident hrelay
        if (tid == 0) {
          while (__hip_atomic_load(xflag, __ATOMIC_RELAXED,
                                   __HIP_MEMORY_SCOPE_AGENT) < s + 1)
            __builtin_amdgcn_s_sleep(2);
        }
        __syncthreads();
#pragma unroll
        for (int it = 0; it < 8; ++it) {
          int ci = it * 512 + tid;
          int row = ci >> 6, cd = ci & 63;
          gload_lds16(hr + (size_t)row * 512 + (cd ^ (row & 7)) * 8, As + ci * 8);
        }
      }
      asm volatile("s_waitcnt vmcnt(0)" ::: "memory");
      __syncthreads();

      f32x4 acc0[4], acc1[4];
#pragma unroll
      for (int m = 0; m < 4; ++m) {
        acc0[m] = (f32x4){0.f, 0.f, 0.f, 0.f};
        acc1[m] = (f32x4){0.f, 0.f, 0.f, 0.f};
      }
#pragma unroll
      for (int m = 0; m < 4; ++m) {
        int row = m * 16 + (l & 15);
#pragma unroll
        for (int kt = 0; kt < 16; ++kt) {
          int c = kt * 4 + (l >> 4);
          f16x8 af = *(const f16x8*)&As[row * 512 + (c ^ (row & 7)) * 8];
          // swapped operands: result col(lane&15) = h-row (sample),
          // row-field = W-row (vocab) -> lane stores 4 consecutive cols
          acc0[m] = __builtin_amdgcn_mfma_f32_16x16x32_f16(
              __builtin_bit_cast(f16x8, w0r[kt]), af, acc0[m], 0, 0, 0);
          if (two)
            acc1[m] = __builtin_amdgcn_mfma_f32_16x16x32_f16(
                __builtin_bit_cast(f16x8, w1r[kt]), af, acc1[m], 0, 0, 0);
        }
      }

#pragma unroll
      for (int m = 0; m < 4; ++m) {
        int b = m * 16 + (l & 15);
        float* orow0 = out + ((size_t)(b * TT + (s - 1))) * VV + n00 + bcol;
        float4 v;
        v.x = acc0[m][0] + bo0.x;
        v.y = acc0[m][1] + bo0.y;
        v.z = acc0[m][2] + bo0.z;
        v.w = acc0[m][3] + bo0.w;
        *(float4*)orow0 = v;
        if (two) {
          float* orow1 = out + ((size_t)(b * TT + (s - 1))) * VV + n01 + bcol;
          float4 v1;
          v1.x = acc1[m][0] + bo1.x;
          v1.y = acc1[m][1] + bo1.y;
          v1.z = acc1[m][2] + bo1.z;
          v1.w = acc1[m][3] + bo1.w;
          *(float4*)orow1 = v1;
        }
      }
    }
  }
}

// ---------------------------------------------------------------------------
extern "C" void kernel_launch(void* const* d_in, const int* in_sizes, int n_in,
                              void* d_out, int out_size, void* d_ws, size_t ws_size,
                              hipStream_t stream) {
  const float* feat = (const float*)d_in[0];
  const int* cap = (const int*)d_in[1];
  // d_in[2] = seq_len (constant 32)
  const float* emb = (const float*)d_in[3];
  const float* Wih = (const float*)d_in[4];
  const float* Whh = (const float*)d_in[5];
  const float* bih = (const float*)d_in[6];
  const float* bhh = (const float*)d_in[7];
  const float* Wout = (const float*)d_in[8];
  const float* bout = (const float*)d_in[9];
  float* out = (float*)d_out;

  char* ws = (char*)d_ws;
  float* Gpre = (float*)ws;                                   // 17,301,504
  char* hseq = ws + 17301504;                                 //  2,162,688 (33 x 64 x 512 fp16)
  int* flags = (int*)(ws + 19464192);                         //     12,288 (spread lines)
  unsigned short* hrelay = (unsigned short*)(ws + 20971520);  // 17,301,504 (8 XCD x 33 x 64KB)

  k_zero<<<dim3(1), dim3(256), 0, stream>>>(flags);
  k_gemm_ih<<<dim3(17 * 16), dim3(256), 0, stream>>>(feat, cap, emb, Wih, bih, bhh, Gpre);
  k_fused<<<dim3(256), dim3(512), 0, stream>>>(Gpre, Whh, Wout, bout, hseq, hrelay, out, flags);
}